// Round 2
// baseline (462.793 us; speedup 1.0000x reference)
//
#include <hip/hip_runtime.h>

// Problem constants
#define Mq   8192     // B*T
#define Hq   1024
#define Sq   1024
#define Tq   1024
#define Vq   5000
#define Vpad 5120     // V padded to multiple of 256 for GEMM2 tiling

typedef __bf16 bf16;
typedef bf16  bf16x8 __attribute__((ext_vector_type(8)));
typedef bf16  bf16x4 __attribute__((ext_vector_type(4)));
typedef float f32x4  __attribute__((ext_vector_type(4)));

typedef const __attribute__((address_space(1))) void* gas_t;
typedef __attribute__((address_space(3))) void*       sas_t;

__device__ __forceinline__ void async_copy16(const void* g, void* s) {
  __builtin_amdgcn_global_load_lds((gas_t)g, (sas_t)s, 16, 0, 0);
}

// ---------------------------------------------------------------------------
// Kernel 1: fused x fp32 -> bf16 cast + p_gen = sigmoid(x @ Wg + bg)
// ---------------------------------------------------------------------------
__global__ __launch_bounds__(256) void pgen_cvt(
    const float* __restrict__ x, const float* __restrict__ Wg,
    const float* __restrict__ bg, bf16* __restrict__ xb,
    float* __restrict__ pgen) {
  const int m = blockIdx.x;
  const int t = threadIdx.x;
  float4 v = ((const float4*)(x + (size_t)m * Hq))[t];
  float4 g = ((const float4*)Wg)[t];
  float dot = v.x * g.x + v.y * g.y + v.z * g.z + v.w * g.w;
  bf16x4 o;
  o[0] = (bf16)v.x; o[1] = (bf16)v.y; o[2] = (bf16)v.z; o[3] = (bf16)v.w;
  ((bf16x4*)(xb + (size_t)m * Hq))[t] = o;
  #pragma unroll
  for (int off = 32; off; off >>= 1) dot += __shfl_down(dot, off, 64);
  __shared__ float red[4];
  if ((t & 63) == 0) red[t >> 6] = dot;
  __syncthreads();
  if (t == 0) {
    float s = red[0] + red[1] + red[2] + red[3] + bg[0];
    pgen[m] = 1.0f / (1.0f + __expf(-s));
  }
}

// ---------------------------------------------------------------------------
// Kernel 2/3: transpose + cast  W[K][Nin] fp32 -> WT[Npad][K] bf16 (zero pad)
// ---------------------------------------------------------------------------
__global__ __launch_bounds__(256) void transpose_cvt(
    const float* __restrict__ W, bf16* __restrict__ WT,
    int K, int Nin, int Npad) {
  __shared__ float tile[32][33];
  const int nb = blockIdx.x * 32, kb = blockIdx.y * 32;
  const int tx = threadIdx.x, ty = threadIdx.y;
  #pragma unroll
  for (int i = 0; i < 32; i += 8) {
    int k = kb + ty + i, n = nb + tx;
    tile[ty + i][tx] = (n < Nin) ? W[(size_t)k * Nin + n] : 0.0f;
  }
  __syncthreads();
  #pragma unroll
  for (int i = 0; i < 32; i += 8) {
    int n = nb + ty + i, k = kb + tx;
    if (n < Npad) WT[(size_t)n * K + k] = (bf16)tile[tx][ty + i];
  }
}

// ---------------------------------------------------------------------------
// 8-phase 256x256 MFMA GEMM (m201-style): C = A @ BT^T (+bias, MODE epilogue)
// MODE 0: gelu_tanh -> bf16 stride N;  MODE 1: exp -> bf16 stride Nstore;
// MODE 2: exp -> fp32 stride Nstore.
// 8 waves (2M x 4N), BK=64, LDS 128KB dbuf, raw s_barrier + counted vmcnt(6),
// XOR slot-swizzle (slot ^= row&7) applied on the pre-swizzled global source
// and on the ds_read address (both-sides involution, rule 21).
// Per K-tile t (buf c=t&1), 4 phases; stage schedule (regions proven consumed
// one phase earlier):
//   P1: reads A f0-3 + B g0-1;  stages B-Q23(t+1) -> buf c^1
//   P2: reads B g2-3;           stages A-Q02(t+2) -> buf c
//   P3: reads A f4-7;           stages B-Q01(t+2) -> buf c
//   P4: (regs only);            stages A-Q13(t+2) -> buf c
// vmcnt(6) at end of P4 (3 half-tiles in flight); vmcnt(0) entering last tile.
// ---------------------------------------------------------------------------
template <int MODE>
__global__ __launch_bounds__(512, 2) void gemm8p(
    const bf16* __restrict__ A, const bf16* __restrict__ BT,
    const float* __restrict__ bias, float* __restrict__ outF,
    bf16* __restrict__ outB, int M, int N, int K, int Nstore) {
  __shared__ bf16 ldsAB[2][2][256 * 64];   // [buf][0=A,1=B] : 128 KiB

  const int tid  = threadIdx.x;
  const int wid  = tid >> 6;
  const int l    = tid & 63;
  const int quad = l >> 4;
  const int t16  = l & 15;
  const int wmh  = wid >> 2;    // 0..1 : which 128-row half of C
  const int wn   = wid & 3;     // 0..3 : which 64-col slice of C

  // XCD-bijective block swizzle (grid sizes here are multiples of 8)
  const int nwg = (int)gridDim.x;
  int wg = (int)blockIdx.x;
  wg = (wg & 7) * (nwg >> 3) + (wg >> 3);
  const int nbx = M >> 8;
  const int by  = wg / nbx;
  const int bx  = wg - by * nbx;
  const int m0  = bx << 8;
  const int n0  = by << 8;

  // staging source (per lane): quarter-row rr in [0,64), slot in [0,8) swizzled
  const int rr  = tid >> 3;
  const int ssw = (tid & 7) ^ (rr & 7);
  const bf16* aSrc = A  + (size_t)(m0 + rr) * K + ssw * 8;
  const bf16* bSrc = BT + (size_t)(n0 + rr) * K + ssw * 8;
  const int ldsW = wid << 9;    // wave-uniform element offset inside a quarter

  // fragment-read bases (elements); swizzled slot for ks=0/1
  const int sx    = t16 & 7;
  const int aRowB = (wmh * 128 + t16) * 64;
  const int bRowB = (wn  * 64  + t16) * 64;
  const int sK0   = ((quad)     ^ sx) << 3;
  const int sK1   = ((4 | quad) ^ sx) << 3;

  const int T = K >> 6;
  f32x4 acc[8][4] = {};

#define STG_A(buf, qk, tt) async_copy16(aSrc + ((size_t)(qk) * 64) * K + (size_t)(tt) * 64, \
    &ldsAB[buf][0][(qk) * 4096 + ldsW])
#define STG_B(buf, qk, tt) async_copy16(bSrc + ((size_t)(qk) * 64) * K + (size_t)(tt) * 64, \
    &ldsAB[buf][1][(qk) * 4096 + ldsW])
#define BAR()   asm volatile("s_barrier" ::: "memory")
#define SBAR()  __builtin_amdgcn_sched_barrier(0)
#define WAITL() asm volatile("s_waitcnt lgkmcnt(0)" ::: "memory")

  // prologue: tile0 fully + tile1 A+B-Q01 (7 pairs = 14 loads)
  STG_A(0, 0, 0); STG_A(0, 2, 0); STG_B(0, 0, 0); STG_B(0, 1, 0);
  STG_A(0, 1, 0); STG_A(0, 3, 0); STG_B(0, 2, 0); STG_B(0, 3, 0);
  STG_A(1, 0, 1); STG_A(1, 2, 1); STG_B(1, 0, 1); STG_B(1, 1, 1);
  STG_A(1, 1, 1); STG_A(1, 3, 1);
  asm volatile("s_waitcnt vmcnt(6)" ::: "memory");   // tile0's 8 loads retired
  BAR();

  #pragma unroll 2
  for (int t = 0; t < T; ++t) {
    const int c  = t & 1;
    const int cn = c ^ 1;
    const bf16* lA = ldsAB[c][0];
    const bf16* lB = ldsAB[c][1];

    bf16x8 a0[4][2], a1[4][2], b0[2][2], b1[2][2];

    // ---------------- P1: read A f0-3, B g0-1 ; stage B-Q23(t+1)
    #pragma unroll
    for (int f = 0; f < 4; ++f) {
      a0[f][0] = *(const bf16x8*)(lA + aRowB + f * 1024 + sK0);
      a0[f][1] = *(const bf16x8*)(lA + aRowB + f * 1024 + sK1);
    }
    #pragma unroll
    for (int g = 0; g < 2; ++g) {
      b0[g][0] = *(const bf16x8*)(lB + bRowB + g * 1024 + sK0);
      b0[g][1] = *(const bf16x8*)(lB + bRowB + g * 1024 + sK1);
    }
    if (t + 1 < T) { STG_B(cn, 2, t + 1); STG_B(cn, 3, t + 1); }
    BAR(); WAITL(); SBAR();
    __builtin_amdgcn_s_setprio(1);
    #pragma unroll
    for (int f = 0; f < 4; ++f)
      #pragma unroll
      for (int g = 0; g < 2; ++g) {
        acc[f][g] = __builtin_amdgcn_mfma_f32_16x16x32_bf16(b0[g][0], a0[f][0], acc[f][g], 0, 0, 0);
        acc[f][g] = __builtin_amdgcn_mfma_f32_16x16x32_bf16(b0[g][1], a0[f][1], acc[f][g], 0, 0, 0);
      }
    SBAR();
    __builtin_amdgcn_s_setprio(0);
    BAR();

    // ---------------- P2: read B g2-3 ; stage A-Q02(t+2)
    #pragma unroll
    for (int g = 0; g < 2; ++g) {
      b1[g][0] = *(const bf16x8*)(lB + bRowB + (g + 2) * 1024 + sK0);
      b1[g][1] = *(const bf16x8*)(lB + bRowB + (g + 2) * 1024 + sK1);
    }
    if (t + 2 < T) { STG_A(c, 0, t + 2); STG_A(c, 2, t + 2); }
    BAR(); WAITL(); SBAR();
    __builtin_amdgcn_s_setprio(1);
    #pragma unroll
    for (int f = 0; f < 4; ++f)
      #pragma unroll
      for (int g = 0; g < 2; ++g) {
        acc[f][g + 2] = __builtin_amdgcn_mfma_f32_16x16x32_bf16(b1[g][0], a0[f][0], acc[f][g + 2], 0, 0, 0);
        acc[f][g + 2] = __builtin_amdgcn_mfma_f32_16x16x32_bf16(b1[g][1], a0[f][1], acc[f][g + 2], 0, 0, 0);
      }
    SBAR();
    __builtin_amdgcn_s_setprio(0);
    BAR();

    // ---------------- P3: read A f4-7 ; stage B-Q01(t+2)
    #pragma unroll
    for (int f = 0; f < 4; ++f) {
      a1[f][0] = *(const bf16x8*)(lA + aRowB + (f + 4) * 1024 + sK0);
      a1[f][1] = *(const bf16x8*)(lA + aRowB + (f + 4) * 1024 + sK1);
    }
    if (t + 2 < T) { STG_B(c, 0, t + 2); STG_B(c, 1, t + 2); }
    BAR(); WAITL(); SBAR();
    __builtin_amdgcn_s_setprio(1);
    #pragma unroll
    for (int f = 0; f < 4; ++f)
      #pragma unroll
      for (int g = 0; g < 2; ++g) {
        acc[f + 4][g + 2] = __builtin_amdgcn_mfma_f32_16x16x32_bf16(b1[g][0], a1[f][0], acc[f + 4][g + 2], 0, 0, 0);
        acc[f + 4][g + 2] = __builtin_amdgcn_mfma_f32_16x16x32_bf16(b1[g][1], a1[f][1], acc[f + 4][g + 2], 0, 0, 0);
      }
    SBAR();
    __builtin_amdgcn_s_setprio(0);
    BAR();

    // ---------------- P4: regs only ; stage A-Q13(t+2) ; vmcnt boundary
    if (t + 2 < T) { STG_A(c, 1, t + 2); STG_A(c, 3, t + 2); }
    BAR(); SBAR();
    __builtin_amdgcn_s_setprio(1);
    #pragma unroll
    for (int f = 0; f < 4; ++f)
      #pragma unroll
      for (int g = 0; g < 2; ++g) {
        acc[f + 4][g] = __builtin_amdgcn_mfma_f32_16x16x32_bf16(b0[g][0], a1[f][0], acc[f + 4][g], 0, 0, 0);
        acc[f + 4][g] = __builtin_amdgcn_mfma_f32_16x16x32_bf16(b0[g][1], a1[f][1], acc[f + 4][g], 0, 0, 0);
      }
    SBAR();
    __builtin_amdgcn_s_setprio(0);
    if (t == T - 2)      { asm volatile("s_waitcnt vmcnt(0)" ::: "memory"); }
    else if (t < T - 2)  { asm volatile("s_waitcnt vmcnt(6)" ::: "memory"); }
    BAR();
  }

#undef STG_A
#undef STG_B
#undef BAR
#undef SBAR
#undef WAITL

  // epilogue (swapped-operand layout): m = m0+wmh*128+f*16+t16,
  //                                    n = n0+wn*64+g*16+quad*4+r
  #pragma unroll
  for (int g = 0; g < 4; ++g) {
    const int nb = n0 + wn * 64 + g * 16 + quad * 4;
    float4 bj = make_float4(0.0f, 0.0f, 0.0f, 0.0f);
    if (MODE == 0 || nb < Nstore) bj = *(const float4*)(bias + nb);
    #pragma unroll
    for (int f = 0; f < 8; ++f) {
      const int mg = m0 + wmh * 128 + f * 16 + t16;
      float v0 = acc[f][g][0] + bj.x;
      float v1 = acc[f][g][1] + bj.y;
      float v2 = acc[f][g][2] + bj.z;
      float v3 = acc[f][g][3] + bj.w;
      if (MODE == 0) {
        float vv[4] = {v0, v1, v2, v3};
        bf16x4 o;
        #pragma unroll
        for (int r = 0; r < 4; ++r) {
          float v  = vv[r];
          float u  = 0.7978845608028654f * (v + 0.044715f * v * v * v);
          float e2 = __expf(2.0f * u);
          float th = 1.0f - 2.0f / (e2 + 1.0f);
          o[r] = (bf16)(0.5f * v * (1.0f + th));
        }
        *(bf16x4*)(outB + (size_t)mg * N + nb) = o;
      } else if (MODE == 1) {
        if (nb < Nstore) {
          bf16x4 o;
          o[0] = (bf16)__expf(v0); o[1] = (bf16)__expf(v1);
          o[2] = (bf16)__expf(v2); o[3] = (bf16)__expf(v3);
          *(bf16x4*)(outB + (size_t)mg * Nstore + nb) = o;
        }
      } else {
        if (nb < Nstore) {
          float4 o = make_float4(__expf(v0), __expf(v1), __expf(v2), __expf(v3));
          *(float4*)(outF + (size_t)mg * Nstore + nb) = o;
        }
      }
    }
  }
}

// ---------------------------------------------------------------------------
// Finalize: out[m][v] = e[m][v] * pg/S  +  sum_{s:nodes[b][s]=v} attn[m][s]*(1-pg)
// ---------------------------------------------------------------------------
template <typename ET>
__global__ __launch_bounds__(256) void finalize(
    float* __restrict__ out, const ET* __restrict__ e,
    const float* __restrict__ pgen, const float* __restrict__ attn,
    const int* __restrict__ nodes) {
  const int m = blockIdx.x;
  const int b = m / Tq;
  const int t = threadIdx.x;
  __shared__ float buf[Vq];
  __shared__ float red[4];

  float s = 0.0f;
  const ET* erow = e + (size_t)m * Vq;
  if constexpr (sizeof(ET) == 2) {
    const bf16x8* e8 = (const bf16x8*)erow;
    for (int i = t; i < Vq / 8; i += 256) {
      bf16x8 v = e8[i];
      #pragma unroll
      for (int k = 0; k < 8; ++k) {
        float f = (float)v[k];
        buf[i * 8 + k] = f;
        s += f;
      }
    }
  } else {
    const float4* e4 = (const float4*)erow;
    for (int i = t; i < Vq / 4; i += 256) {
      float4 v = e4[i];
      buf[i * 4 + 0] = v.x; buf[i * 4 + 1] = v.y;
      buf[i * 4 + 2] = v.z; buf[i * 4 + 3] = v.w;
      s += (v.x + v.y) + (v.z + v.w);
    }
  }
  #pragma unroll
  for (int off = 32; off; off >>= 1) s += __shfl_down(s, off, 64);
  if ((t & 63) == 0) red[t >> 6] = s;
  __syncthreads();
  s = red[0] + red[1] + red[2] + red[3];

  const float pg    = pgen[m];
  const float scale = pg / s;
  const float coef  = (1.0f - pg) / scale;

  const float* arow = attn + (size_t)m * Sq;
  const int*   nrow = nodes + (size_t)b * Sq;
  for (int sIdx = t; sIdx < Sq; sIdx += 256)
    atomicAdd(&buf[nrow[sIdx]], arow[sIdx] * coef);
  __syncthreads();

  float4* o4 = (float4*)(out + (size_t)m * Vq);
  const float4* b4 = (const float4*)buf;
  for (int i = t; i < Vq / 4; i += 256) {
    float4 v = b4[i];
    v.x *= scale; v.y *= scale; v.z *= scale; v.w *= scale;
    o4[i] = v;
  }
}

// ---------------------------------------------------------------------------
extern "C" void kernel_launch(void* const* d_in, const int* in_sizes, int n_in,
                              void* d_out, int out_size, void* d_ws, size_t ws_size,
                              hipStream_t stream) {
  const float* x    = (const float*)d_in[0];
  const float* attn = (const float*)d_in[1];
  const int*   nodes= (const int*)d_in[2];
  const float* Wg   = (const float*)d_in[3];
  const float* bg   = (const float*)d_in[4];
  const float* Wf   = (const float*)d_in[5];
  const float* bf_  = (const float*)d_in[6];
  const float* Wv   = (const float*)d_in[7];
  const float* bv   = (const float*)d_in[8];
  float* out = (float*)d_out;

  char* w = (char*)d_ws;

  const size_t NEED = 111312896ull;
  const bool big = ws_size >= NEED;

  const int g1 = (Mq / 256) * (Hq / 256);      // 128 blocks
  const int g2 = (Mq / 256) * (Vpad / 256);    // 640 blocks

  if (big) {
    bf16*  eB   = (bf16*)(w);
    bf16*  xb   = (bf16*)(w);
    bf16*  hB   = (bf16*)(w + 81920000ull);
    bf16*  WfT  = (bf16*)(w + 98697216ull);
    bf16*  WvT  = (bf16*)(w + 100794368ull);
    float* pgen = (float*)(w + 111280128ull);

    pgen_cvt<<<Mq, 256, 0, stream>>>(x, Wg, bg, xb, pgen);
    transpose_cvt<<<dim3(Hq / 32, Hq / 32), dim3(32, 8), 0, stream>>>(Wf, WfT, Hq, Hq, Hq);
    transpose_cvt<<<dim3(Vpad / 32, Hq / 32), dim3(32, 8), 0, stream>>>(Wv, WvT, Hq, Vq, Vpad);
    gemm8p<0><<<g1, 512, 0, stream>>>(xb, WfT, bf_, nullptr, hB, Mq, Hq, Hq, Hq);
    gemm8p<1><<<g2, 512, 0, stream>>>(hB, WvT, bv, nullptr, eB, Mq, Vpad, Hq, Vq);
    finalize<bf16><<<Mq, 256, 0, stream>>>(out, eB, pgen, attn, nodes);
  } else {
    bf16*  xb   = (bf16*)(w);
    bf16*  hB   = (bf16*)(w + 16777216);
    bf16*  WfT  = (bf16*)(w + 33554432);
    bf16*  WvT  = (bf16*)(w + 35651584);
    float* pgen = (float*)(w + 46137344);

    pgen_cvt<<<Mq, 256, 0, stream>>>(x, Wg, bg, xb, pgen);
    transpose_cvt<<<dim3(Hq / 32, Hq / 32), dim3(32, 8), 0, stream>>>(Wf, WfT, Hq, Hq, Hq);
    transpose_cvt<<<dim3(Vpad / 32, Hq / 32), dim3(32, 8), 0, stream>>>(Wv, WvT, Hq, Vq, Vpad);
    gemm8p<0><<<g1, 512, 0, stream>>>(xb, WfT, bf_, nullptr, hB, Mq, Hq, Hq, Hq);
    gemm8p<2><<<g2, 512, 0, stream>>>(hB, WvT, bv, out, nullptr, Mq, Vpad, Hq, Vq);
    finalize<float><<<Mq, 256, 0, stream>>>(out, out, pgen, attn, nodes);
  }
}

// Round 4
// 452.744 us; speedup vs baseline: 1.0222x; 1.0222x over previous
//
#include <hip/hip_runtime.h>

// Problem constants
#define Mq   8192     // B*T
#define Hq   1024
#define Sq   1024
#define Tq   1024
#define Vq   5000
#define Vpad 5120     // V padded to multiple of 256 for GEMM2 tiling

typedef __bf16 bf16;
typedef bf16  bf16x8 __attribute__((ext_vector_type(8)));
typedef bf16  bf16x4 __attribute__((ext_vector_type(4)));
typedef float f32x4  __attribute__((ext_vector_type(4)));

typedef const __attribute__((address_space(1))) void* gas_t;
typedef __attribute__((address_space(3))) void*       sas_t;
typedef const __attribute__((address_space(3))) bf16* lds3_t;

__device__ __forceinline__ void async_copy16(const void* g, void* s) {
  __builtin_amdgcn_global_load_lds((gas_t)g, (sas_t)s, 16, 0, 0);
}

// Opaque LDS read: hides the LDS access from the compiler's waitcnt pass so it
// cannot insert a conservative vmcnt(0) (global_load_lds alias drain) before it.
// Safety: caller provides s_waitcnt lgkmcnt(0) + sched_barrier(0) before use,
// and counted vmcnt guarantees the staged data has landed (manual schedule).
__device__ __forceinline__ bf16x8 ldsr16(const bf16* p) {
  bf16x8 r;
  asm volatile("ds_read_b128 %0, %1" : "=v"(r) : "v"((lds3_t)p));
  return r;
}

// ---------------------------------------------------------------------------
// Kernel 1: fused x fp32 -> bf16 cast + p_gen = sigmoid(x @ Wg + bg)
// ---------------------------------------------------------------------------
__global__ __launch_bounds__(256) void pgen_cvt(
    const float* __restrict__ x, const float* __restrict__ Wg,
    const float* __restrict__ bg, bf16* __restrict__ xb,
    float* __restrict__ pgen) {
  const int m = blockIdx.x;
  const int t = threadIdx.x;
  float4 v = ((const float4*)(x + (size_t)m * Hq))[t];
  float4 g = ((const float4*)Wg)[t];
  float dot = v.x * g.x + v.y * g.y + v.z * g.z + v.w * g.w;
  bf16x4 o;
  o[0] = (bf16)v.x; o[1] = (bf16)v.y; o[2] = (bf16)v.z; o[3] = (bf16)v.w;
  ((bf16x4*)(xb + (size_t)m * Hq))[t] = o;
  #pragma unroll
  for (int off = 32; off; off >>= 1) dot += __shfl_down(dot, off, 64);
  __shared__ float red[4];
  if ((t & 63) == 0) red[t >> 6] = dot;
  __syncthreads();
  if (t == 0) {
    float s = red[0] + red[1] + red[2] + red[3] + bg[0];
    pgen[m] = 1.0f / (1.0f + __expf(-s));
  }
}

// ---------------------------------------------------------------------------
// Kernel 2/3: transpose + cast  W[K][Nin] fp32 -> WT[Npad][K] bf16 (zero pad)
// ---------------------------------------------------------------------------
__global__ __launch_bounds__(256) void transpose_cvt(
    const float* __restrict__ W, bf16* __restrict__ WT,
    int K, int Nin, int Npad) {
  __shared__ float tile[32][33];
  const int nb = blockIdx.x * 32, kb = blockIdx.y * 32;
  const int tx = threadIdx.x, ty = threadIdx.y;
  #pragma unroll
  for (int i = 0; i < 32; i += 8) {
    int k = kb + ty + i, n = nb + tx;
    tile[ty + i][tx] = (n < Nin) ? W[(size_t)k * Nin + n] : 0.0f;
  }
  __syncthreads();
  #pragma unroll
  for (int i = 0; i < 32; i += 8) {
    int n = nb + ty + i, k = kb + tx;
    if (n < Npad) WT[(size_t)n * K + k] = (bf16)tile[tx][ty + i];
  }
}

// ---------------------------------------------------------------------------
// 2-phase 128x128 MFMA GEMM (proven 695 TF): C = A @ BT^T (+bias epilogue)
// MODE 0: gelu->bf16 stride N; MODE 1: exp->bf16 stride Nstore; MODE 2: exp->f32
// Swapped-operand mfma => per-thread acc = 4 consecutive cols of one row.
// ---------------------------------------------------------------------------
template <int MODE>
__global__ __launch_bounds__(256, 2) void gemm_mfma(
    const bf16* __restrict__ A, const bf16* __restrict__ BT,
    const float* __restrict__ bias, float* __restrict__ outF,
    bf16* __restrict__ outB, int M, int N, int K, int Nstore) {
  __shared__ bf16 As[2][128 * 32];
  __shared__ bf16 Bs[2][128 * 32];
  const int tid  = threadIdx.x;
  const int w    = tid >> 6;
  const int l    = tid & 63;
  const int quad = l >> 4;
  const int t16  = l & 15;
  const int wm   = (w >> 1) * 64;
  const int wn   = (w & 1) * 64;
  const int m0   = blockIdx.x * 128;
  const int n0   = blockIdx.y * 128;
  const int srow = l >> 2;
  const int scol = (l & 3) * 8;

  f32x4 acc[4][4] = {};

  const int row0 = (w * 16) + srow;
  const int row1 = ((4 + w) * 16) + srow;
  const bf16* aP0 = A  + (size_t)(m0 + row0) * K + scol;
  const bf16* aP1 = A  + (size_t)(m0 + row1) * K + scol;
  const bf16* bP0 = BT + (size_t)(n0 + row0) * K + scol;
  const bf16* bP1 = BT + (size_t)(n0 + row1) * K + scol;
  const int ldsOff0 = (w)     * 512;
  const int ldsOff1 = (4 + w) * 512;

  async_copy16(aP0, As[0] + ldsOff0);
  async_copy16(bP0, Bs[0] + ldsOff0);
  async_copy16(aP1, As[0] + ldsOff1);
  async_copy16(bP1, Bs[0] + ldsOff1);
  __syncthreads();

  int cur = 0;
  for (int k0 = 0; k0 < K; k0 += 32) {
    if (k0 + 32 < K) {
      const int nxt = cur ^ 1;
      async_copy16(aP0 + k0 + 32, As[nxt] + ldsOff0);
      async_copy16(bP0 + k0 + 32, Bs[nxt] + ldsOff0);
      async_copy16(aP1 + k0 + 32, As[nxt] + ldsOff1);
      async_copy16(bP1 + k0 + 32, Bs[nxt] + ldsOff1);
    }

    bf16x8 af[4], bfr[4];
    #pragma unroll
    for (int i = 0; i < 4; ++i)
      af[i] = *(const bf16x8*)(As[cur] + (wm + 16 * i + t16) * 32 + quad * 8);
    #pragma unroll
    for (int j = 0; j < 4; ++j)
      bfr[j] = *(const bf16x8*)(Bs[cur] + (wn + 16 * j + t16) * 32 + quad * 8);
    #pragma unroll
    for (int i = 0; i < 4; ++i)
      #pragma unroll
      for (int j = 0; j < 4; ++j)
        acc[i][j] = __builtin_amdgcn_mfma_f32_16x16x32_bf16(bfr[j], af[i], acc[i][j], 0, 0, 0);

    __syncthreads();
    cur ^= 1;
  }

  #pragma unroll
  for (int j = 0; j < 4; ++j) {
    const int nb = n0 + wn + 16 * j + quad * 4;
    float4 bj4 = make_float4(0.0f, 0.0f, 0.0f, 0.0f);
    if (MODE == 0 || nb < Nstore) bj4 = *(const float4*)(bias + nb);
    #pragma unroll
    for (int i = 0; i < 4; ++i) {
      const int mg = m0 + wm + 16 * i + t16;
      float v0 = acc[i][j][0] + bj4.x;
      float v1 = acc[i][j][1] + bj4.y;
      float v2 = acc[i][j][2] + bj4.z;
      float v3 = acc[i][j][3] + bj4.w;
      if (MODE == 0) {
        float vv[4] = {v0, v1, v2, v3};
        bf16x4 o;
        #pragma unroll
        for (int r = 0; r < 4; ++r) {
          float v  = vv[r];
          float u  = 0.7978845608028654f * (v + 0.044715f * v * v * v);
          float e2 = __expf(2.0f * u);
          float th = 1.0f - 2.0f / (e2 + 1.0f);
          o[r] = (bf16)(0.5f * v * (1.0f + th));
        }
        *(bf16x4*)(outB + (size_t)mg * N + nb) = o;
      } else if (MODE == 1) {
        if (nb < Nstore) {
          bf16x4 o;
          o[0] = (bf16)__expf(v0); o[1] = (bf16)__expf(v1);
          o[2] = (bf16)__expf(v2); o[3] = (bf16)__expf(v3);
          *(bf16x4*)(outB + (size_t)mg * Nstore + nb) = o;
        }
      } else {
        if (nb < Nstore) {
          float4 o = make_float4(__expf(v0), __expf(v1), __expf(v2), __expf(v3));
          *(float4*)(outF + (size_t)mg * Nstore + nb) = o;
        }
      }
    }
  }
}

// ---------------------------------------------------------------------------
// 8-phase 256x256 MFMA GEMM v2: opaque asm ds_read (no compiler alias drains),
// counted vmcnt(6), setprio, XOR LDS swizzle, supertile XCD swizzle.
// Requires (M/256)%8==0 and (N/256)%4==0.
// ---------------------------------------------------------------------------
template <int MODE>
__global__ __launch_bounds__(512, 1) void gemm8p(
    const bf16* __restrict__ A, const bf16* __restrict__ BT,
    const float* __restrict__ bias, float* __restrict__ outF,
    bf16* __restrict__ outB, int M, int N, int K, int Nstore) {
  __shared__ bf16 ldsAB[2][2][256 * 64];   // [buf][0=A,1=B] : 128 KiB

  const int tid  = threadIdx.x;
  const int wid  = tid >> 6;
  const int l    = tid & 63;
  const int quad = l >> 4;
  const int t16  = l & 15;
  const int wmh  = wid >> 2;
  const int wn   = wid & 3;

  // XCD-contiguous + 32-block supertile (8 bx x 4 by): co-resident working set
  // = 8 A-panels + 4 B-panels ~ 4.25 MB ~ one XCD L2.
  const int nwg = (int)gridDim.x;
  const int cpx = nwg >> 3;
  int f0 = ((int)blockIdx.x & 7) * cpx + ((int)blockIdx.x >> 3);
  const int nbx  = M >> 8;
  const int sbxn = nbx >> 3;
  const int st = f0 >> 5, r0 = f0 & 31;
  const int bx = (st % sbxn) * 8 + (r0 & 7);
  const int by = (st / sbxn) * 4 + (r0 >> 3);
  const int m0 = bx << 8;
  const int n0 = by << 8;

  // staging source: quarter-row rr in [0,64), slot swizzled (involution with read)
  const int rr  = tid >> 3;
  const int ssw = (tid & 7) ^ (rr & 7);
  const bf16* aSrc = A  + (size_t)(m0 + rr) * K + ssw * 8;
  const bf16* bSrc = BT + (size_t)(n0 + rr) * K + ssw * 8;
  const int ldsW = wid << 9;

  const int sx    = t16 & 7;
  const int aRowB = (wmh * 128 + t16) * 64;
  const int bRowB = (wn  * 64  + t16) * 64;
  const int sK0   = ((quad)     ^ sx) << 3;
  const int sK1   = ((4 | quad) ^ sx) << 3;

  const int T = K >> 6;
  f32x4 acc[8][4] = {};

#define STG_A(buf, qk, tt) async_copy16(aSrc + ((size_t)(qk) * 64) * K + (size_t)(tt) * 64, \
    &ldsAB[buf][0][(qk) * 4096 + ldsW])
#define STG_B(buf, qk, tt) async_copy16(bSrc + ((size_t)(qk) * 64) * K + (size_t)(tt) * 64, \
    &ldsAB[buf][1][(qk) * 4096 + ldsW])
#define BAR()   asm volatile("s_barrier" ::: "memory")
#define SBAR()  __builtin_amdgcn_sched_barrier(0)
#define WAITL() asm volatile("s_waitcnt lgkmcnt(0)" ::: "memory")

  // prologue: tile0 fully (8 loads) + tile1 A + B-Q01 (6 loads)
  STG_A(0, 0, 0); STG_A(0, 2, 0); STG_B(0, 0, 0); STG_B(0, 1, 0);
  STG_A(0, 1, 0); STG_A(0, 3, 0); STG_B(0, 2, 0); STG_B(0, 3, 0);
  STG_A(1, 0, 1); STG_A(1, 2, 1); STG_B(1, 0, 1); STG_B(1, 1, 1);
  STG_A(1, 1, 1); STG_A(1, 3, 1);
  asm volatile("s_waitcnt vmcnt(6)" ::: "memory");
  BAR();

  for (int t = 0; t < T; ++t) {
    const int c  = t & 1;
    const int cn = c ^ 1;
    const bf16* lA = ldsAB[c][0];
    const bf16* lB = ldsAB[c][1];

    bf16x8 a0[4][2], a1[4][2], b0[2][2], b1[2][2];

    // ---------------- P1: read A f0-3, B g0-1 ; stage B-Q23(t+1) -> buf cn
    #pragma unroll
    for (int ff = 0; ff < 4; ++ff) {
      a0[ff][0] = ldsr16(lA + aRowB + ff * 1024 + sK0);
      a0[ff][1] = ldsr16(lA + aRowB + ff * 1024 + sK1);
    }
    #pragma unroll
    for (int g = 0; g < 2; ++g) {
      b0[g][0] = ldsr16(lB + bRowB + g * 1024 + sK0);
      b0[g][1] = ldsr16(lB + bRowB + g * 1024 + sK1);
    }
    if (t + 1 < T) { STG_B(cn, 2, t + 1); STG_B(cn, 3, t + 1); }
    BAR(); WAITL(); SBAR();
    __builtin_amdgcn_s_setprio(1);
    #pragma unroll
    for (int ff = 0; ff < 4; ++ff)
      #pragma unroll
      for (int g = 0; g < 2; ++g) {
        acc[ff][g] = __builtin_amdgcn_mfma_f32_16x16x32_bf16(b0[g][0], a0[ff][0], acc[ff][g], 0, 0, 0);
        acc[ff][g] = __builtin_amdgcn_mfma_f32_16x16x32_bf16(b0[g][1], a0[ff][1], acc[ff][g], 0, 0, 0);
      }
    SBAR();
    __builtin_amdgcn_s_setprio(0);
    BAR();

    // ---------------- P2: read B g2-3 ; stage A-Q02(t+2) -> buf c
    #pragma unroll
    for (int g = 0; g < 2; ++g) {
      b1[g][0] = ldsr16(lB + bRowB + (g + 2) * 1024 + sK0);
      b1[g][1] = ldsr16(lB + bRowB + (g + 2) * 1024 + sK1);
    }
    if (t + 2 < T) { STG_A(c, 0, t + 2); STG_A(c, 2, t + 2); }
    BAR(); WAITL(); SBAR();
    __builtin_amdgcn_s_setprio(1);
    #pragma unroll
    for (int ff = 0; ff < 4; ++ff)
      #pragma unroll
      for (int g = 0; g < 2; ++g) {
        acc[ff][g + 2] = __builtin_amdgcn_mfma_f32_16x16x32_bf16(b1[g][0], a0[ff][0], acc[ff][g + 2], 0, 0, 0);
        acc[ff][g + 2] = __builtin_amdgcn_mfma_f32_16x16x32_bf16(b1[g][1], a0[ff][1], acc[ff][g + 2], 0, 0, 0);
      }
    SBAR();
    __builtin_amdgcn_s_setprio(0);
    BAR();

    // ---------------- P3: read A f4-7 ; stage B-Q01(t+2) -> buf c
    #pragma unroll
    for (int ff = 0; ff < 4; ++ff) {
      a1[ff][0] = ldsr16(lA + aRowB + (ff + 4) * 1024 + sK0);
      a1[ff][1] = ldsr16(lA + aRowB + (ff + 4) * 1024 + sK1);
    }
    if (t + 2 < T) { STG_B(c, 0, t + 2); STG_B(c, 1, t + 2); }
    BAR(); WAITL(); SBAR();
    __builtin_amdgcn_s_setprio(1);
    #pragma unroll
    for (int ff = 0; ff < 4; ++ff)
      #pragma unroll
      for (int g = 0; g < 2; ++g) {
        acc[ff + 4][g + 2] = __builtin_amdgcn_mfma_f32_16x16x32_bf16(b1[g][0], a1[ff][0], acc[ff + 4][g + 2], 0, 0, 0);
        acc[ff + 4][g + 2] = __builtin_amdgcn_mfma_f32_16x16x32_bf16(b1[g][1], a1[ff][1], acc[ff + 4][g + 2], 0, 0, 0);
      }
    SBAR();
    __builtin_amdgcn_s_setprio(0);
    BAR();

    // ---------------- P4: regs only ; stage A-Q13(t+2) ; vmcnt boundary
    if (t + 2 < T) { STG_A(c, 1, t + 2); STG_A(c, 3, t + 2); }
    BAR(); SBAR();
    __builtin_amdgcn_s_setprio(1);
    #pragma unroll
    for (int ff = 0; ff < 4; ++ff)
      #pragma unroll
      for (int g = 0; g < 2; ++g) {
        acc[ff + 4][g] = __builtin_amdgcn_mfma_f32_16x16x32_bf16(b0[g][0], a1[ff][0], acc[ff + 4][g], 0, 0, 0);
        acc[ff + 4][g] = __builtin_amdgcn_mfma_f32_16x16x32_bf16(b0[g][1], a1[ff][1], acc[ff + 4][g], 0, 0, 0);
      }
    SBAR();
    __builtin_amdgcn_s_setprio(0);
    if (t == T - 2)      { asm volatile("s_waitcnt vmcnt(0)" ::: "memory"); }
    else if (t < T - 2)  { asm volatile("s_waitcnt vmcnt(6)" ::: "memory"); }
    BAR();
  }

#undef STG_A
#undef STG_B
#undef BAR
#undef SBAR
#undef WAITL

  // epilogue: m = m0+wmh*128+f*16+t16, n = n0+wn*64+g*16+quad*4+r
  #pragma unroll
  for (int g = 0; g < 4; ++g) {
    const int nb = n0 + wn * 64 + g * 16 + quad * 4;
    float4 bj = make_float4(0.0f, 0.0f, 0.0f, 0.0f);
    if (MODE == 0 || nb < Nstore) bj = *(const float4*)(bias + nb);
    #pragma unroll
    for (int ff = 0; ff < 8; ++ff) {
      const int mg = m0 + wmh * 128 + ff * 16 + t16;
      float v0 = acc[ff][g][0] + bj.x;
      float v1 = acc[ff][g][1] + bj.y;
      float v2 = acc[ff][g][2] + bj.z;
      float v3 = acc[ff][g][3] + bj.w;
      if (MODE == 1) {
        if (nb < Nstore) {
          bf16x4 o;
          o[0] = (bf16)__expf(v0); o[1] = (bf16)__expf(v1);
          o[2] = (bf16)__expf(v2); o[3] = (bf16)__expf(v3);
          *(bf16x4*)(outB + (size_t)mg * Nstore + nb) = o;
        }
      } else if (MODE == 2) {
        if (nb < Nstore) {
          float4 o = make_float4(__expf(v0), __expf(v1), __expf(v2), __expf(v3));
          *(float4*)(outF + (size_t)mg * Nstore + nb) = o;
        }
      }
    }
  }
}

// ---------------------------------------------------------------------------
// Finalize: out[m][v] = e[m][v] * pg/S  +  sum_{s:nodes[b][s]=v} attn[m][s]*(1-pg)
// ---------------------------------------------------------------------------
template <typename ET>
__global__ __launch_bounds__(256) void finalize(
    float* __restrict__ out, const ET* __restrict__ e,
    const float* __restrict__ pgen, const float* __restrict__ attn,
    const int* __restrict__ nodes) {
  const int m = blockIdx.x;
  const int b = m / Tq;
  const int t = threadIdx.x;
  __shared__ float buf[Vq];
  __shared__ float red[4];

  float s = 0.0f;
  const ET* erow = e + (size_t)m * Vq;
  if constexpr (sizeof(ET) == 2) {
    const bf16x8* e8 = (const bf16x8*)erow;
    float4* b4w = (float4*)buf;
    for (int i = t; i < Vq / 8; i += 256) {
      bf16x8 v = e8[i];
      float4 lo, hi;
      lo.x = (float)v[0]; lo.y = (float)v[1]; lo.z = (float)v[2]; lo.w = (float)v[3];
      hi.x = (float)v[4]; hi.y = (float)v[5]; hi.z = (float)v[6]; hi.w = (float)v[7];
      b4w[2 * i]     = lo;
      b4w[2 * i + 1] = hi;
      s += (lo.x + lo.y) + (lo.z + lo.w) + (hi.x + hi.y) + (hi.z + hi.w);
    }
  } else {
    const float4* e4 = (const float4*)erow;
    float4* b4w = (float4*)buf;
    for (int i = t; i < Vq / 4; i += 256) {
      float4 v = e4[i];
      b4w[i] = v;
      s += (v.x + v.y) + (v.z + v.w);
    }
  }
  #pragma unroll
  for (int off = 32; off; off >>= 1) s += __shfl_down(s, off, 64);
  if ((t & 63) == 0) red[t >> 6] = s;
  __syncthreads();
  s = red[0] + red[1] + red[2] + red[3];

  const float pg    = pgen[m];
  const float scale = pg / s;
  const float coef  = (1.0f - pg) / scale;

  const float* arow = attn + (size_t)m * Sq;
  const int*   nrow = nodes + (size_t)b * Sq;
  for (int sIdx = t; sIdx < Sq; sIdx += 256)
    atomicAdd(&buf[nrow[sIdx]], arow[sIdx] * coef);
  __syncthreads();

  float4* o4 = (float4*)(out + (size_t)m * Vq);
  const float4* b4 = (const float4*)buf;
  for (int i = t; i < Vq / 4; i += 256) {
    float4 v = b4[i];
    v.x *= scale; v.y *= scale; v.z *= scale; v.w *= scale;
    o4[i] = v;
  }
}

// ---------------------------------------------------------------------------
extern "C" void kernel_launch(void* const* d_in, const int* in_sizes, int n_in,
                              void* d_out, int out_size, void* d_ws, size_t ws_size,
                              hipStream_t stream) {
  const float* x    = (const float*)d_in[0];
  const float* attn = (const float*)d_in[1];
  const int*   nodes= (const int*)d_in[2];
  const float* Wg   = (const float*)d_in[3];
  const float* bg   = (const float*)d_in[4];
  const float* Wf   = (const float*)d_in[5];
  const float* bf_  = (const float*)d_in[6];
  const float* Wv   = (const float*)d_in[7];
  const float* bv   = (const float*)d_in[8];
  float* out = (float*)d_out;

  char* w = (char*)d_ws;

  const size_t NEED = 111312896ull;
  const bool big = ws_size >= NEED;

  const int g2 = (Mq / 256) * (Vpad / 256);    // 640 blocks (8-phase)

  if (big) {
    bf16*  eB   = (bf16*)(w);
    bf16*  xb   = (bf16*)(w);
    bf16*  hB   = (bf16*)(w + 81920000ull);
    bf16*  WfT  = (bf16*)(w + 98697216ull);
    bf16*  WvT  = (bf16*)(w + 100794368ull);
    float* pgen = (float*)(w + 111280128ull);

    pgen_cvt<<<Mq, 256, 0, stream>>>(x, Wg, bg, xb, pgen);
    transpose_cvt<<<dim3(Hq / 32, Hq / 32), dim3(32, 8), 0, stream>>>(Wf, WfT, Hq, Hq, Hq);
    transpose_cvt<<<dim3(Vpad / 32, Hq / 32), dim3(32, 8), 0, stream>>>(Wv, WvT, Hq, Vq, Vpad);
    gemm_mfma<0><<<dim3(Mq / 128, Hq / 128), 256, 0, stream>>>(
        xb, WfT, bf_, nullptr, hB, Mq, Hq, Hq, Hq);
    gemm8p<1><<<g2, 512, 0, stream>>>(hB, WvT, bv, nullptr, eB, Mq, Vpad, Hq, Vq);
    finalize<bf16><<<Mq, 256, 0, stream>>>(out, eB, pgen, attn, nodes);
  } else {
    bf16*  xb   = (bf16*)(w);
    bf16*  hB   = (bf16*)(w + 16777216);
    bf16*  WfT  = (bf16*)(w + 33554432);
    bf16*  WvT  = (bf16*)(w + 35651584);
    float* pgen = (float*)(w + 46137344);

    pgen_cvt<<<Mq, 256, 0, stream>>>(x, Wg, bg, xb, pgen);
    transpose_cvt<<<dim3(Hq / 32, Hq / 32), dim3(32, 8), 0, stream>>>(Wf, WfT, Hq, Hq, Hq);
    transpose_cvt<<<dim3(Vpad / 32, Hq / 32), dim3(32, 8), 0, stream>>>(Wv, WvT, Hq, Vq, Vpad);
    gemm_mfma<0><<<dim3(Mq / 128, Hq / 128), 256, 0, stream>>>(
        xb, WfT, bf_, nullptr, hB, Mq, Hq, Hq, Hq);
    gemm_mfma<2><<<dim3(Mq / 128, Vpad / 128), 256, 0, stream>>>(
        hB, WvT, bv, out, nullptr, Mq, Vpad, Hq, Vq);
    finalize<float><<<Mq, 256, 0, stream>>>(out, out, pgen, attn, nodes);
  }
}

// Round 5
// 442.435 us; speedup vs baseline: 1.0460x; 1.0233x over previous
//
#include <hip/hip_runtime.h>

// Problem constants
#define Mq   8192     // B*T
#define Hq   1024
#define Sq   1024
#define Tq   1024
#define Vq   5000
#define Vpad 5120     // V padded for GEMM2 tiling

typedef __bf16 bf16;
typedef bf16  bf16x8 __attribute__((ext_vector_type(8)));
typedef bf16  bf16x4 __attribute__((ext_vector_type(4)));
typedef float f32x4  __attribute__((ext_vector_type(4)));

typedef const __attribute__((address_space(1))) void* gas_t;
typedef __attribute__((address_space(3))) void*       sas_t;

__device__ __forceinline__ void async_copy16(const void* g, void* s) {
  __builtin_amdgcn_global_load_lds((gas_t)g, (sas_t)s, 16, 0, 0);
}

// ---------------------------------------------------------------------------
// Kernel 1: fused x fp32 -> bf16 cast + p_gen = sigmoid(x @ Wg + bg)
// wave-per-row: 4 rows per 256-thread block, no LDS, no __syncthreads
// ---------------------------------------------------------------------------
__global__ __launch_bounds__(256) void pgen_cvt(
    const float* __restrict__ x, const float* __restrict__ Wg,
    const float* __restrict__ bg, bf16* __restrict__ xb,
    float* __restrict__ pgen) {
  const int m    = blockIdx.x * 4 + (threadIdx.x >> 6);
  const int lane = threadIdx.x & 63;
  const float4* xr = (const float4*)(x + (size_t)m * Hq);
  const float4* gr = (const float4*)Wg;
  bf16x4* xo = (bf16x4*)(xb + (size_t)m * Hq);
  float dot = 0.0f;
  #pragma unroll
  for (int k = 0; k < 4; ++k) {
    float4 v = xr[lane + 64 * k];
    float4 g = gr[lane + 64 * k];
    dot += v.x * g.x + v.y * g.y + v.z * g.z + v.w * g.w;
    bf16x4 o;
    o[0] = (bf16)v.x; o[1] = (bf16)v.y; o[2] = (bf16)v.z; o[3] = (bf16)v.w;
    xo[lane + 64 * k] = o;
  }
  #pragma unroll
  for (int off = 32; off; off >>= 1) dot += __shfl_down(dot, off, 64);
  if (lane == 0) pgen[m] = 1.0f / (1.0f + __expf(-(dot + bg[0])));
}

// ---------------------------------------------------------------------------
// Kernel 2/3: transpose + cast  W[K][Nin] fp32 -> WT[Npad][K] bf16 (zero pad)
// ---------------------------------------------------------------------------
__global__ __launch_bounds__(256) void transpose_cvt(
    const float* __restrict__ W, bf16* __restrict__ WT,
    int K, int Nin, int Npad) {
  __shared__ float tile[32][33];
  const int nb = blockIdx.x * 32, kb = blockIdx.y * 32;
  const int tx = threadIdx.x, ty = threadIdx.y;
  #pragma unroll
  for (int i = 0; i < 32; i += 8) {
    int k = kb + ty + i, n = nb + tx;
    tile[ty + i][tx] = (n < Nin) ? W[(size_t)k * Nin + n] : 0.0f;
  }
  __syncthreads();
  #pragma unroll
  for (int i = 0; i < 32; i += 8) {
    int n = nb + ty + i, k = kb + tx;
    if (n < Npad) WT[(size_t)n * K + k] = (bf16)tile[tx][ty + i];
  }
}

// ---------------------------------------------------------------------------
// 2-phase 128x128 MFMA GEMM (proven 695 TF): C = A @ BT^T (+bias epilogue)
// MODE 0: gelu->bf16 stride N; MODE 1: exp->bf16 stride Nstore; MODE 2: exp->f32
// Swapped-operand mfma => per-thread acc = 4 consecutive cols of one row.
// ---------------------------------------------------------------------------
template <int MODE>
__global__ __launch_bounds__(256, 2) void gemm_mfma(
    const bf16* __restrict__ A, const bf16* __restrict__ BT,
    const float* __restrict__ bias, float* __restrict__ outF,
    bf16* __restrict__ outB, int M, int N, int K, int Nstore) {
  __shared__ bf16 As[2][128 * 32];
  __shared__ bf16 Bs[2][128 * 32];
  const int tid  = threadIdx.x;
  const int w    = tid >> 6;
  const int l    = tid & 63;
  const int quad = l >> 4;
  const int t16  = l & 15;
  const int wm   = (w >> 1) * 64;
  const int wn   = (w & 1) * 64;
  const int m0   = blockIdx.x * 128;
  const int n0   = blockIdx.y * 128;
  const int srow = l >> 2;
  const int scol = (l & 3) * 8;

  f32x4 acc[4][4] = {};

  const int row0 = (w * 16) + srow;
  const int row1 = ((4 + w) * 16) + srow;
  const bf16* aP0 = A  + (size_t)(m0 + row0) * K + scol;
  const bf16* aP1 = A  + (size_t)(m0 + row1) * K + scol;
  const bf16* bP0 = BT + (size_t)(n0 + row0) * K + scol;
  const bf16* bP1 = BT + (size_t)(n0 + row1) * K + scol;
  const int ldsOff0 = (w)     * 512;
  const int ldsOff1 = (4 + w) * 512;

  async_copy16(aP0, As[0] + ldsOff0);
  async_copy16(bP0, Bs[0] + ldsOff0);
  async_copy16(aP1, As[0] + ldsOff1);
  async_copy16(bP1, Bs[0] + ldsOff1);
  __syncthreads();

  int cur = 0;
  for (int k0 = 0; k0 < K; k0 += 32) {
    if (k0 + 32 < K) {
      const int nxt = cur ^ 1;
      async_copy16(aP0 + k0 + 32, As[nxt] + ldsOff0);
      async_copy16(bP0 + k0 + 32, Bs[nxt] + ldsOff0);
      async_copy16(aP1 + k0 + 32, As[nxt] + ldsOff1);
      async_copy16(bP1 + k0 + 32, Bs[nxt] + ldsOff1);
    }

    bf16x8 af[4], bfr[4];
    #pragma unroll
    for (int i = 0; i < 4; ++i)
      af[i] = *(const bf16x8*)(As[cur] + (wm + 16 * i + t16) * 32 + quad * 8);
    #pragma unroll
    for (int j = 0; j < 4; ++j)
      bfr[j] = *(const bf16x8*)(Bs[cur] + (wn + 16 * j + t16) * 32 + quad * 8);
    #pragma unroll
    for (int i = 0; i < 4; ++i)
      #pragma unroll
      for (int j = 0; j < 4; ++j)
        acc[i][j] = __builtin_amdgcn_mfma_f32_16x16x32_bf16(bfr[j], af[i], acc[i][j], 0, 0, 0);

    __syncthreads();
    cur ^= 1;
  }

  #pragma unroll
  for (int j = 0; j < 4; ++j) {
    const int nb = n0 + wn + 16 * j + quad * 4;
    float4 bj4 = make_float4(0.0f, 0.0f, 0.0f, 0.0f);
    if (MODE == 0 || nb < Nstore) bj4 = *(const float4*)(bias + nb);
    #pragma unroll
    for (int i = 0; i < 4; ++i) {
      const int mg = m0 + wm + 16 * i + t16;
      float v0 = acc[i][j][0] + bj4.x;
      float v1 = acc[i][j][1] + bj4.y;
      float v2 = acc[i][j][2] + bj4.z;
      float v3 = acc[i][j][3] + bj4.w;
      if (MODE == 0) {
        float vv[4] = {v0, v1, v2, v3};
        bf16x4 o;
        #pragma unroll
        for (int r = 0; r < 4; ++r) {
          float v  = vv[r];
          float u  = 0.7978845608028654f * (v + 0.044715f * v * v * v);
          float e2 = __expf(2.0f * u);
          float th = 1.0f - 2.0f / (e2 + 1.0f);
          o[r] = (bf16)(0.5f * v * (1.0f + th));
        }
        *(bf16x4*)(outB + (size_t)mg * N + nb) = o;
      } else if (MODE == 1) {
        if (nb < Nstore) {
          bf16x4 o;
          o[0] = (bf16)__expf(v0); o[1] = (bf16)__expf(v1);
          o[2] = (bf16)__expf(v2); o[3] = (bf16)__expf(v3);
          *(bf16x4*)(outB + (size_t)mg * Nstore + nb) = o;
        }
      } else {
        if (nb < Nstore) {
          float4 o = make_float4(__expf(v0), __expf(v1), __expf(v2), __expf(v3));
          *(float4*)(outF + (size_t)mg * Nstore + nb) = o;
        }
      }
    }
  }
}

// ---------------------------------------------------------------------------
// finalize2 (bf16 e, big-ws path): one 512-thread block per row m.
//   out[v] = e[v]*(pg/S) + sum_{s:nodes[b][s]=v} attn[m][s]*(1-pg)
// e held in REGISTERS (no LDS round-trip); LDS only holds the zero-filled
// scatter buffer; attn/nodes/pgen issued at kernel start (issue-early);
// scatter only needs (1-pg) so it does not wait on the row-sum. 2 barriers.
// e layout: 625 bf16x8 per row; thread t owns i=t (all) and i=512+t (t<113).
// ---------------------------------------------------------------------------
__global__ __launch_bounds__(512) void finalize2(
    float* __restrict__ out, const bf16* __restrict__ e,
    const float* __restrict__ pgen, const float* __restrict__ attn,
    const int* __restrict__ nodes) {
  const int m = blockIdx.x;
  const int b = m >> 10;            // Tq = 1024
  const int t = threadIdx.x;
  __shared__ float buf[Vq];
  __shared__ float red[8];

  // zero scatter buffer (independent of all loads)
  float4* b4 = (float4*)buf;
  #pragma unroll
  for (int k = 0; k < 3; ++k) {
    int i = t + 512 * k;
    if (i < Vq / 4) b4[i] = make_float4(0.0f, 0.0f, 0.0f, 0.0f);
  }

  // issue-early: pgen, attn, nodes
  const float pg = pgen[m];
  const float* arow = attn + (size_t)m * Sq;
  const int*   nrow = nodes + (size_t)b * Sq;
  const float a0 = arow[t];
  const float a1 = arow[t + 512];
  const int   n0i = nrow[t];
  const int   n1i = nrow[t + 512];

  // e -> registers + running sum
  const bf16x8* e8 = (const bf16x8*)(e + (size_t)m * Vq);
  const bf16x8 ev0 = e8[t];
  const bool   has1 = (t < 113);
  bf16x8 ev1 = {};
  if (has1) ev1 = e8[512 + t];

  float s = 0.0f;
  float f0[8], f1[8];
  #pragma unroll
  for (int k = 0; k < 8; ++k) { f0[k] = (float)ev0[k]; s += f0[k]; }
  #pragma unroll
  for (int k = 0; k < 8; ++k) { f1[k] = (float)ev1[k]; }
  if (has1) {
    #pragma unroll
    for (int k = 0; k < 8; ++k) s += f1[k];
  }
  #pragma unroll
  for (int off = 32; off; off >>= 1) s += __shfl_down(s, off, 64);
  if ((t & 63) == 0) red[t >> 6] = s;

  __syncthreads();   // zero-fill + red visible

  // scatter (needs only pg)
  const float ci = 1.0f - pg;
  atomicAdd(&buf[n0i], a0 * ci);
  atomicAdd(&buf[n1i], a1 * ci);

  float S = 0.0f;
  #pragma unroll
  for (int k = 0; k < 8; ++k) S += red[k];
  const float scale = pg / S;

  __syncthreads();   // atomics visible

  // out = e*scale + buf
  float4* o4 = (float4*)(out + (size_t)m * Vq);
  {
    float4 lo = make_float4(f0[0] * scale + buf[t * 8 + 0],
                            f0[1] * scale + buf[t * 8 + 1],
                            f0[2] * scale + buf[t * 8 + 2],
                            f0[3] * scale + buf[t * 8 + 3]);
    float4 hi = make_float4(f0[4] * scale + buf[t * 8 + 4],
                            f0[5] * scale + buf[t * 8 + 5],
                            f0[6] * scale + buf[t * 8 + 6],
                            f0[7] * scale + buf[t * 8 + 7]);
    o4[2 * t]     = lo;
    o4[2 * t + 1] = hi;
  }
  if (has1) {
    const int base = (512 + t) * 8;
    float4 lo = make_float4(f1[0] * scale + buf[base + 0],
                            f1[1] * scale + buf[base + 1],
                            f1[2] * scale + buf[base + 2],
                            f1[3] * scale + buf[base + 3]);
    float4 hi = make_float4(f1[4] * scale + buf[base + 4],
                            f1[5] * scale + buf[base + 5],
                            f1[6] * scale + buf[base + 6],
                            f1[7] * scale + buf[base + 7]);
    o4[2 * (512 + t)]     = lo;
    o4[2 * (512 + t) + 1] = hi;
  }
}

// ---------------------------------------------------------------------------
// finalize (fp32 fallback, in-place per-row): unchanged proven version
// ---------------------------------------------------------------------------
__global__ __launch_bounds__(256) void finalize_f32(
    float* __restrict__ out, const float* __restrict__ e,
    const float* __restrict__ pgen, const float* __restrict__ attn,
    const int* __restrict__ nodes) {
  const int m = blockIdx.x;
  const int b = m / Tq;
  const int t = threadIdx.x;
  __shared__ float buf[Vq];
  __shared__ float red[4];

  float s = 0.0f;
  const float* erow = e + (size_t)m * Vq;
  const float4* e4 = (const float4*)erow;
  float4* b4w = (float4*)buf;
  for (int i = t; i < Vq / 4; i += 256) {
    float4 v = e4[i];
    b4w[i] = v;
    s += (v.x + v.y) + (v.z + v.w);
  }
  #pragma unroll
  for (int off = 32; off; off >>= 1) s += __shfl_down(s, off, 64);
  if ((t & 63) == 0) red[t >> 6] = s;
  __syncthreads();
  s = red[0] + red[1] + red[2] + red[3];

  const float pg    = pgen[m];
  const float scale = pg / s;
  const float coef  = (1.0f - pg) / scale;

  const float* arow = attn + (size_t)m * Sq;
  const int*   nrow = nodes + (size_t)b * Sq;
  for (int sIdx = t; sIdx < Sq; sIdx += 256)
    atomicAdd(&buf[nrow[sIdx]], arow[sIdx] * coef);
  __syncthreads();

  float4* o4 = (float4*)(out + (size_t)m * Vq);
  const float4* b4 = (const float4*)buf;
  for (int i = t; i < Vq / 4; i += 256) {
    float4 v = b4[i];
    v.x *= scale; v.y *= scale; v.z *= scale; v.w *= scale;
    o4[i] = v;
  }
}

// ---------------------------------------------------------------------------
extern "C" void kernel_launch(void* const* d_in, const int* in_sizes, int n_in,
                              void* d_out, int out_size, void* d_ws, size_t ws_size,
                              hipStream_t stream) {
  const float* x    = (const float*)d_in[0];
  const float* attn = (const float*)d_in[1];
  const int*   nodes= (const int*)d_in[2];
  const float* Wg   = (const float*)d_in[3];
  const float* bg   = (const float*)d_in[4];
  const float* Wf   = (const float*)d_in[5];
  const float* bf_  = (const float*)d_in[6];
  const float* Wv   = (const float*)d_in[7];
  const float* bv   = (const float*)d_in[8];
  float* out = (float*)d_out;

  char* w = (char*)d_ws;

  const size_t NEED = 111312896ull;
  const bool big = ws_size >= NEED;

  if (big) {
    bf16*  eB   = (bf16*)(w);
    bf16*  xb   = (bf16*)(w);
    bf16*  hB   = (bf16*)(w + 81920000ull);
    bf16*  WfT  = (bf16*)(w + 98697216ull);
    bf16*  WvT  = (bf16*)(w + 100794368ull);
    float* pgen = (float*)(w + 111280128ull);

    pgen_cvt<<<Mq / 4, 256, 0, stream>>>(x, Wg, bg, xb, pgen);
    transpose_cvt<<<dim3(Hq / 32, Hq / 32), dim3(32, 8), 0, stream>>>(Wf, WfT, Hq, Hq, Hq);
    transpose_cvt<<<dim3(Vpad / 32, Hq / 32), dim3(32, 8), 0, stream>>>(Wv, WvT, Hq, Vq, Vpad);
    gemm_mfma<0><<<dim3(Mq / 128, Hq / 128), 256, 0, stream>>>(
        xb, WfT, bf_, nullptr, hB, Mq, Hq, Hq, Hq);
    // gemm2 split into two M-halves (attribution: anything slower than a half
    // will surface in the top-5 profile)
    gemm_mfma<1><<<dim3(Mq / 256, Vpad / 128), 256, 0, stream>>>(
        hB, WvT, bv, nullptr, eB, Mq / 2, Vpad, Hq, Vq);
    gemm_mfma<1><<<dim3(Mq / 256, Vpad / 128), 256, 0, stream>>>(
        hB + (size_t)(Mq / 2) * Hq, WvT, bv, nullptr,
        eB + (size_t)(Mq / 2) * Vq, Mq / 2, Vpad, Hq, Vq);
    finalize2<<<Mq, 512, 0, stream>>>(out, eB, pgen, attn, nodes);
  } else {
    bf16*  xb   = (bf16*)(w);
    bf16*  hB   = (bf16*)(w + 16777216);
    bf16*  WfT  = (bf16*)(w + 33554432);
    bf16*  WvT  = (bf16*)(w + 35651584);
    float* pgen = (float*)(w + 46137344);

    pgen_cvt<<<Mq / 4, 256, 0, stream>>>(x, Wg, bg, xb, pgen);
    transpose_cvt<<<dim3(Hq / 32, Hq / 32), dim3(32, 8), 0, stream>>>(Wf, WfT, Hq, Hq, Hq);
    transpose_cvt<<<dim3(Vpad / 32, Hq / 32), dim3(32, 8), 0, stream>>>(Wv, WvT, Hq, Vq, Vpad);
    gemm_mfma<0><<<dim3(Mq / 128, Hq / 128), 256, 0, stream>>>(
        xb, WfT, bf_, nullptr, hB, Mq, Hq, Hq, Hq);
    gemm_mfma<2><<<dim3(Mq / 128, Vpad / 128), 256, 0, stream>>>(
        hB, WvT, bv, out, nullptr, Mq, Vpad, Hq, Vq);
    finalize_f32<<<Mq, 256, 0, stream>>>(out, out, pgen, attn, nodes);
  }
}